// Round 2
// baseline (116.968 us; speedup 1.0000x reference)
//
#include <hip/hip_runtime.h>

// Problem constants (match reference)
#define B 8
#define S 2048
#define N 512
#define D 1024
#define MAX_W 32
#define MASK_FILL -1000.0f

typedef float vfloat4 __attribute__((ext_vector_type(4)));
// NOTE: amdgcn builtins (cvt_pkrtz, fdot2) traffic in __fp16 vectors, not _Float16
typedef __fp16 half2v __attribute__((ext_vector_type(2)));
typedef unsigned int uint;

// pack two f32 -> f16x2 (v_cvt_pkrtz_f16_f32: 1 op instead of 2 cvt + pack)
__device__ inline uint pack_f16x2(float x, float y) {
#if __has_builtin(__builtin_amdgcn_cvt_pkrtz)
    half2v r = __builtin_amdgcn_cvt_pkrtz(x, y);
    return __builtin_bit_cast(uint, r);
#else
    half2v r; r[0] = (__fp16)x; r[1] = (__fp16)y;
    return __builtin_bit_cast(uint, r);
#endif
}

// f16x2 dot with f32 accumulator: v_dot2_f32_f16 (gfx906+, 1 instr = 2 FMA)
__device__ inline float dot2(uint a, uint b, float c) {
    half2v x = __builtin_bit_cast(half2v, a);
    half2v y = __builtin_bit_cast(half2v, b);
#if __has_builtin(__builtin_amdgcn_fdot2)
    return __builtin_amdgcn_fdot2(x, y, c, false);
#else
    return c + (float)x[0] * (float)y[0] + (float)x[1] * (float)y[1];
#endif
}

// ---------------------------------------------------------------------------
// Kernel 1 (prep): logits + fp16 compression of seq, one pass over seq.
// R8 structure (linear row map, one wave/row, float4 loads). HBM-bound:
// 64 MB read + 32 MB write ~= 15 us floor — at it. R13: bf16 -> fp16
// (same bytes, more mantissa) so pool can use v_dot2_f32_f16.
// ---------------------------------------------------------------------------
__global__ __launch_bounds__(512) void prep_kernel(
    const float* __restrict__ seq,
    const float* __restrict__ att_w,
    const float* __restrict__ att_b,
    float* __restrict__ logits,
    unsigned short* __restrict__ seqh)
{
    const int row  = blockIdx.x * 8 + (threadIdx.x >> 6);   // 8 waves/block
    const int lane = threadIdx.x & 63;

    const float4* rp = (const float4*)(seq + (size_t)row * D);
    const float4* wp = (const float4*)att_w;

    float4 a[4];
    float acc = 0.0f;
#pragma unroll
    for (int k = 0; k < 4; ++k) {
        a[k] = rp[lane + 64 * k];
        const float4 w = wp[lane + 64 * k];
        acc += a[k].x * w.x + a[k].y * w.y + a[k].z * w.z + a[k].w * w.w;
    }

    uint2* hp = (uint2*)(seqh + (size_t)row * D);
#pragma unroll
    for (int k = 0; k < 4; ++k) {
        uint2 h;
        h.x = pack_f16x2(a[k].x, a[k].y);
        h.y = pack_f16x2(a[k].z, a[k].w);
        hp[lane + 64 * k] = h;
    }

#pragma unroll
    for (int off = 32; off > 0; off >>= 1)
        acc += __shfl_down(acc, off);
    if (lane == 0)
        logits[row] = acc + att_b[0];
}

// ---------------------------------------------------------------------------
// Kernel 2: per-span masked softmax + pooling over fp16 rows, 16 B loads.
// One block (256 threads) per span; 128 lanes cover a 2 KB row, block
// processes TWO rows concurrently (half = tid>>7) — R11 structure.
// R12: padded entries clamp gather index to START (weight exactly 0,
// in-span row -> L1 hit instead of cold fetch).
// R13: theory = pool is VALU-issue-bound (2 ops/element: unpack + fmac),
// not byte-bound (164 MB L2 gather ~ 5 us floor).
//   - fp16 rows + v_perm_b32 row-pairing + v_dot2_f32_f16: 1 op/element.
//   - attn weights pre-packed as half2 pairs (attn[w], attn[w+2]) in LDS.
//   - LDS holds 32-bit BYTE offsets -> cheap address arithmetic.
//   - explicit next-iteration prefetch (trip <= 4, runtime bound).
// Predicted: pool ~40 -> ~27 us, total ~117 -> ~103 us; bytes unchanged.
// ---------------------------------------------------------------------------
__global__ __launch_bounds__(256) void pool_kernel(
    const unsigned short* __restrict__ seqh,
    const int*   __restrict__ spans,
    const float* __restrict__ logits,
    float* __restrict__ out)
{
    const int b    = blockIdx.x & 7;        // batch -> XCD affinity
    const int n    = blockIdx.x >> 3;       // span within batch
    const int span = b * N + n;

    const int start = spans[2 * span + 0];
    const int end   = spans[2 * span + 1];  // inclusive
    const int width = end - start;          // valid entries = width + 1

    __shared__ uint  s_ah2[MAX_W];          // half2 (attn[w], attn[w+2])
    __shared__ uint  s_off[MAX_W];          // row byte-offset in batch slice
    __shared__ float s_part[128][9];        // padded: stride 9 vs 32 banks

    const int tid  = threadIdx.x;
    const int c    = tid & 127;             // 16 B col-slice (8 f16) owner
    const int half = tid >> 7;              // 0: even rows, 1: odd rows

    if (tid < MAX_W) {
        const int w   = tid;
        const int raw = end - w;
        const bool valid = (w <= width) && (raw >= 0);
        // valid entries: raw >= start -> idx = raw (matches reference).
        // padded entries: weight exactly 0; point at start (L1-hit dup).
        const int idx = raw > start ? raw : start;
        const float l = valid ? logits[b * S + idx] : MASK_FILL;

        float m = l;
#pragma unroll
        for (int off = 16; off > 0; off >>= 1)
            m = fmaxf(m, __shfl_down(m, off, 32));
        m = __shfl(m, 0, 32);

        const float p = __expf(l - m);

        float sum = p;
#pragma unroll
        for (int off = 16; off > 0; off >>= 1)
            sum += __shfl_down(sum, off, 32);
        sum = __shfl(sum, 0, 32);

        const float at  = p / sum;          // exactly 0 for masked entries
        const float at2 = __shfl_down(at, 2, 32);  // attn[w+2] (w>=30 unused)
        s_ah2[w] = pack_f16x2(at, at2);
        s_off[w] = (uint)idx << 11;         // idx * D * sizeof(f16)
    }
    __syncthreads();

    const char* sb  = (const char*)seqh + (size_t)b * S * D * 2;
    const uint  cvo = (uint)c * 16u;

    float acc[8];
#pragma unroll
    for (int j = 0; j < 8; ++j) acc[j] = 0.0f;

    const int cnt  = width + 1;             // wave-uniform per block
    const int cnt8 = (cnt + 7) & ~7;        // <= 32

#define LDROW(OFF) (*(const uint4*)(sb + (OFF) + cvo))

    // rows this thread handles at step w: w+half, w+2+half, w+4+half, w+6+half
    uint4 q0 = LDROW(s_off[half + 0]);
    uint4 q1 = LDROW(s_off[half + 2]);
    uint4 q2 = LDROW(s_off[half + 4]);
    uint4 q3 = LDROW(s_off[half + 6]);

    for (int w = 0; w < cnt8; w += 8) {
        const uint aA = s_ah2[w + half + 0];   // (attn[w0], attn[w0+2])
        const uint aB = s_ah2[w + half + 4];   // (attn[w0+4], attn[w0+6])

        uint4 n0, n1, n2, n3;
        const bool more = (w + 8) < cnt8;      // wave-uniform branch
        if (more) {
            const int v0 = w + 8 + half;
            n0 = LDROW(s_off[v0 + 0]);
            n1 = LDROW(s_off[v0 + 2]);
            n2 = LDROW(s_off[v0 + 4]);
            n3 = LDROW(s_off[v0 + 6]);
        }

        // perm(S0=qy, S1=qx, 0x05040100) -> half2(qx.h0, qy.h0)  (even d)
        // perm(S0=qy, S1=qx, 0x07060302) -> half2(qx.h1, qy.h1)  (odd d)
        // pairs with aA/aB = half2(attn_row_qx, attn_row_qy)
#define PAIR(qx, qy, ah, jlo, jhi)                                          \
        acc[jlo] = dot2(ah, __builtin_amdgcn_perm(qy, qx, 0x05040100u),     \
                        acc[jlo]);                                          \
        acc[jhi] = dot2(ah, __builtin_amdgcn_perm(qy, qx, 0x07060302u),     \
                        acc[jhi]);

        PAIR(q0.x, q1.x, aA, 0, 1)
        PAIR(q0.y, q1.y, aA, 2, 3)
        PAIR(q0.z, q1.z, aA, 4, 5)
        PAIR(q0.w, q1.w, aA, 6, 7)
        PAIR(q2.x, q3.x, aB, 0, 1)
        PAIR(q2.y, q3.y, aB, 2, 3)
        PAIR(q2.z, q3.z, aB, 4, 5)
        PAIR(q2.w, q3.w, aB, 6, 7)
#undef PAIR

        if (more) { q0 = n0; q1 = n1; q2 = n2; q3 = n3; }
    }
#undef LDROW

    // merge odd-row partials into even-row threads, then store
    if (half == 1) {
#pragma unroll
        for (int j = 0; j < 8; ++j) s_part[c][j] = acc[j];
    }
    __syncthreads();
    if (half == 0) {
#pragma unroll
        for (int j = 0; j < 8; ++j) acc[j] += s_part[c][j];

        // thread c owns fp32 out cols [8c, 8c+8): two NT float4 stores
        vfloat4 va;
        va.x = acc[0]; va.y = acc[1]; va.z = acc[2]; va.w = acc[3];
        vfloat4* op = ((vfloat4*)(out + (size_t)span * D)) + 2 * c;
        __builtin_nontemporal_store(va, op);
        va.x = acc[4]; va.y = acc[5]; va.z = acc[6]; va.w = acc[7];
        __builtin_nontemporal_store(va, op + 1);
    }
}

// ---------------------------------------------------------------------------
extern "C" void kernel_launch(void* const* d_in, const int* in_sizes, int n_in,
                              void* d_out, int out_size, void* d_ws, size_t ws_size,
                              hipStream_t stream)
{
    const float* seq    = (const float*)d_in[0];  // (B,S,D) f32
    const int*   spans  = (const int*)  d_in[1];  // (B,N,2) i32
    const float* att_w  = (const float*)d_in[2];  // (D,1)   f32
    const float* att_b  = (const float*)d_in[3];  // (1,)    f32

    float* out    = (float*)d_out;                // (B,N,D) f32
    float* logits = (float*)d_ws;                 // (B,S)   f32   (64 KB)
    unsigned short* seqh =
        (unsigned short*)((char*)d_ws + (size_t)B * S * sizeof(float)); // 32 MB f16

    prep_kernel<<<(B * S) / 8, 512, 0, stream>>>(seq, att_w, att_b,
                                                 logits, seqh);
    pool_kernel<<<B * N, 256, 0, stream>>>(seqh, spans, logits, out);
}